// Round 5
// baseline (144001.160 us; speedup 1.0000x reference)
//
#include <hip/hip_runtime.h>

// ---------------- problem constants ----------------
#define BB   64
#define TT   512
#define NVOC 16
#define KIN  256
#define HH   512
#define GG   2048
#define FF   64

#define NWG  256
#define NTHR 512

// LDS layout (float offsets); weight rows padded to 524 floats.
#define U1W_OFF  0
#define W2W_OFF  8384        // 16*524
#define U2W_OFF  16768
#define HLDS_OFF 25152       // [32][64 float4], XOR-swizzled
#define ZRED_OFF 33344       // [8][32][17]
#define TABW_OFF 37696       // [16][16]
#define B2W_OFF  37952       // [16]
#define LDS_FLOATS 37968
#define LDS_BYTES  (LDS_FLOATS * 4)

// ws layout: 32 KB flag region, then floats: h1[2][BB*HH], h2[2][BB*HH].
// One flag per WG (64B-padded line), monotonic step stamps, zeroed per launch.
#define FLAG_WORDS 8192
#define H1_OFF 0
#define H2_OFF 65536

// ---- IC-direct (sc1, L2-bypassing) primitives: relaxed agent atomics ----
static __device__ __forceinline__ float2 ic_load2(const float* p) {
  unsigned long long v = __hip_atomic_load((const unsigned long long*)p,
      __ATOMIC_RELAXED, __HIP_MEMORY_SCOPE_AGENT);
  float2 r;
  r.x = __uint_as_float((unsigned)(v & 0xffffffffULL));
  r.y = __uint_as_float((unsigned)(v >> 32));
  return r;
}
static __device__ __forceinline__ void ic_store(float* p, float v) {
  __hip_atomic_store((unsigned*)p, __float_as_uint(v),
                     __ATOMIC_RELAXED, __HIP_MEMORY_SCOPE_AGENT);
}

// wait: threads 0..127 each poll one WG flag (distinct 64B lines) with a
// plain relaxed sc1 load — NO cache invalidate per poll (R4's failure mode).
__device__ __forceinline__ void bar_wait(unsigned* flags, unsigned target) {
  if (threadIdx.x < 128) {
    unsigned* f = flags + threadIdx.x * 16;
    while (__hip_atomic_load(f, __ATOMIC_RELAXED, __HIP_MEMORY_SCOPE_AGENT) < target)
      __builtin_amdgcn_s_sleep(2);
  }
  __syncthreads();
}

// publish: drain own stores (sc1 stores are globally visible at vmcnt retire),
// join all threads, then one relaxed flag store. No release fence -> no wbl2.
__device__ __forceinline__ void bar_publish(unsigned* myflag, unsigned val) {
  asm volatile("s_waitcnt vmcnt(0)" ::: "memory");
  __syncthreads();
  if (threadIdx.x == 0)
    __hip_atomic_store(myflag, val, __ATOMIC_RELAXED, __HIP_MEMORY_SCOPE_AGENT);
}

// ---- h-chunk staging: IC [32][512] slice (256-col chunk) -> regs ----
__device__ __forceinline__ void stage_ld(float4 v[4], const float* __restrict__ src, int tid) {
  #pragma unroll
  for (int jj = 0; jj < 4; ++jj) {
    int f4 = jj * 512 + tid;
    int b = f4 >> 6, k4l = f4 & 63;
    const float* p = src + b * HH + k4l * 4;
    float2 lo = ic_load2(p);
    float2 hi = ic_load2(p + 2);
    v[jj] = make_float4(lo.x, lo.y, hi.x, hi.y);
  }
}
__device__ __forceinline__ void stage_st(float* __restrict__ hlds, const float4 v[4], int tid) {
  float4* h4 = reinterpret_cast<float4*>(hlds);
  #pragma unroll
  for (int jj = 0; jj < 4; ++jj) {
    int f4 = jj * 512 + tid;
    int b = f4 >> 6, k4l = f4 & 63;
    h4[b * 64 + (k4l ^ (b >> 3))] = v[jj];   // slot-XOR: reads conflict-free
  }
}

// ---- single-weight inner: 8 j-iters, 9 LDS reads / 32 FMA ----
__device__ __forceinline__ void inner8(float acc[8], const float* __restrict__ wrow,
                                       const float4* __restrict__ h4base, int kq8, int bg) {
  #pragma unroll
  for (int j = 0; j < 8; ++j) {
    int k4 = kq8 + j;
    float4 w = *reinterpret_cast<const float4*>(wrow + k4 * 4);
    const float4* hb = h4base + (k4 ^ bg);
    #pragma unroll
    for (int r = 0; r < 8; ++r) {
      float4 h = hb[r * 64];
      acc[r] += h.x * w.x; acc[r] += h.y * w.y;
      acc[r] += h.z * w.z; acc[r] += h.w * w.w;
    }
  }
}

// ---- dual-weight inner (U1 & W2 share h1 reads): 10 LDS reads / 64 FMA ----
__device__ __forceinline__ void inner8_dual(float a1[8], float a2[8],
                                            const float* __restrict__ wA,
                                            const float* __restrict__ wB,
                                            const float4* __restrict__ h4base,
                                            int kq8, int bg) {
  #pragma unroll
  for (int j = 0; j < 8; ++j) {
    int k4 = kq8 + j;
    float4 u = *reinterpret_cast<const float4*>(wA + k4 * 4);
    float4 w = *reinterpret_cast<const float4*>(wB + k4 * 4);
    const float4* hb = h4base + (k4 ^ bg);
    #pragma unroll
    for (int r = 0; r < 8; ++r) {
      float4 h = hb[r * 64];
      a1[r] += h.x * u.x; a1[r] += h.y * u.y;
      a1[r] += h.z * u.z; a1[r] += h.w * u.w;
      a2[r] += h.x * w.x; a2[r] += h.y * w.y;
      a2[r] += h.z * w.z; a2[r] += h.w * w.w;
    }
  }
}

extern "C" __global__ void __launch_bounds__(NTHR, 2)
lstm_fused5(const int* __restrict__ tokens, const float* __restrict__ emb,
            const float* __restrict__ W1, const float* __restrict__ U1,
            const float* __restrict__ b1, const float* __restrict__ W2,
            const float* __restrict__ U2, const float* __restrict__ b2,
            const float* __restrict__ Wd, const float* __restrict__ bd,
            float* __restrict__ out, float* __restrict__ wsf,
            unsigned* __restrict__ flags)
{
  extern __shared__ float lds[];
  float* u1w  = lds + U1W_OFF;
  float* w2w  = lds + W2W_OFF;
  float* u2w  = lds + U2W_OFF;
  float* hlds = lds + HLDS_OFF;
  float* zred = lds + ZRED_OFF;
  float* tabw = lds + TABW_OFF;
  float* b2w  = lds + B2W_OFF;

  const int wg  = blockIdx.x;
  const int tid = threadIdx.x;
  const int bh  = wg >> 7;        // batch half: rows bh*32..+31
  const int ct  = wg & 127;       // col tile: hidden cols ct*4..+3
  const int hc0 = ct * 4;
  const int zcl = tid & 15;       // gate g=zcl>>2, col c=zcl&3
  const int bg  = (tid >> 4) & 3; // 8-row batch group
  const int kq  = tid >> 6;       // wave id = K-split (8-way)
  const int kq8 = kq * 8;

  unsigned* fHalf = flags + bh * 2048;     // this half's 128 flags
  unsigned* myF   = fHalf + ct * 16;

  float* h1base = wsf + H1_OFF;            // [2][BB*HH], gen g in buf[g&1]
  float* h2base = wsf + H2_OFF;

  // ---------------- phase 0 ----------------
  { // weight slices -> LDS, transposed to [zc][k] rows of 524
    int k = tid;
    #pragma unroll
    for (int g = 0; g < 4; ++g) {
      float4 a = *reinterpret_cast<const float4*>(U1 + (size_t)k * GG + hc0 + 512 * g);
      u1w[(g * 4 + 0) * 524 + k] = a.x; u1w[(g * 4 + 1) * 524 + k] = a.y;
      u1w[(g * 4 + 2) * 524 + k] = a.z; u1w[(g * 4 + 3) * 524 + k] = a.w;
      float4 b_ = *reinterpret_cast<const float4*>(W2 + (size_t)k * GG + hc0 + 512 * g);
      w2w[(g * 4 + 0) * 524 + k] = b_.x; w2w[(g * 4 + 1) * 524 + k] = b_.y;
      w2w[(g * 4 + 2) * 524 + k] = b_.z; w2w[(g * 4 + 3) * 524 + k] = b_.w;
      float4 c_ = *reinterpret_cast<const float4*>(U2 + (size_t)k * GG + hc0 + 512 * g);
      u2w[(g * 4 + 0) * 524 + k] = c_.x; u2w[(g * 4 + 1) * 524 + k] = c_.y;
      u2w[(g * 4 + 2) * 524 + k] = c_.z; u2w[(g * 4 + 3) * 524 + k] = c_.w;
    }
  }
  if (tid < 256) { // token->z1 table for this WG's 16 z-cols (vocab=16)
    int v = tid >> 4, zz = tid & 15;
    int col = hc0 + (zz & 3) + ((zz >> 2) << 9);
    float a = b1[col];
    #pragma unroll 4
    for (int k = 0; k < KIN; ++k) a += emb[v * KIN + k] * W1[(size_t)k * GG + col];
    tabw[v * 16 + zz] = a;
  }
  if (tid < 16) b2w[tid] = b2[hc0 + (tid & 3) + ((tid >> 2) << 9)];

  const int fb = tid >> 2;          // finalize batch row (local, tid<128)
  const int fc = tid & 3;           // finalize hidden col (local)

  // h2(-1) = 0 lives in buf[1]; store via IC so consumers' sc1 loads see it.
  if (tid < 128)
    ic_store(h2base + BB * HH + (bh * 32 + fb) * HH + hc0 + fc, 0.f);
  __syncthreads();                  // tabw/b2w/weights ready

  float c1 = 0.f, hp1 = 0.f, c2 = 0.f, hp2 = 0.f;

  // ---------------- tick 0: h1(0) from table only (h1(-1)=0) ----------------
  if (tid < 128) {
    int tok = tokens[(bh * 32 + fb) * TT + 0];
    float z0 = tabw[tok * 16 + 0 * 4 + fc];
    float z1 = tabw[tok * 16 + 1 * 4 + fc];
    float z2 = tabw[tok * 16 + 2 * 4 + fc];
    float z3 = tabw[tok * 16 + 3 * 4 + fc];
    float si = 1.f / (1.f + expf(-z0));
    float sf = 1.f / (1.f + expf(-z1));
    float gg = tanhf(z2);
    float so = 1.f / (1.f + expf(-z3));
    float cn = sf * c1 + si * gg;
    float hn = so * tanhf(cn);
    if (tok == 0) { cn = c1; hn = hp1; }
    c1 = cn; hp1 = hn;
    ic_store(h1base + (bh * 32 + fb) * HH + hc0 + fc, hn);   // gen 0 -> buf[0]
  }
  bar_publish(myF, 2u);

  const float4* h4base = reinterpret_cast<const float4*>(hlds) + bg * 512;
  const float* u1row = u1w + zcl * 524;
  const float* w2row = w2w + zcl * 524;
  const float* u2row = u2w + zcl * 524;

  // ---------------- ticks 1..512: L1(t) fused with L2(t-1) ----------------
  for (int t = 1; t <= TT; ++t) {
    bar_wait(fHalf, (unsigned)t + 1u);   // all WGs finished tick t-1

    const float* h1r = h1base + ((t - 1) & 1) * BB * HH + bh * 32 * HH; // h1(t-1)
    const float* h2r = h2base + (t & 1) * BB * HH + bh * 32 * HH;       // h2(t-2)
    float* h1w = h1base + (t & 1) * BB * HH;                            // h1(t)
    float* h2w = h2base + ((t - 1) & 1) * BB * HH;                      // h2(t-1)

    float acc1[8] = {0,0,0,0,0,0,0,0};
    float acc2[8] = {0,0,0,0,0,0,0,0};
    float4 pre[4];

    // ---- h1 chunk 0 ----
    stage_ld(pre, h1r, tid);
    __syncthreads(); stage_st(hlds, pre, tid); __syncthreads();
    stage_ld(pre, h1r + 256, tid);                    // chunk 1 in flight
    inner8_dual(acc1, acc2, u1row, w2row, h4base, kq8, bg);
    __syncthreads(); stage_st(hlds, pre, tid); __syncthreads();
    stage_ld(pre, h2r, tid);                          // h2 chunk 0 in flight
    inner8_dual(acc1, acc2, u1row + 256, w2row + 256, h4base, kq8, bg);
    __syncthreads(); stage_st(hlds, pre, tid); __syncthreads();
    stage_ld(pre, h2r + 256, tid);                    // h2 chunk 1 in flight
    inner8(acc2, u2row, h4base, kq8, bg);
    __syncthreads(); stage_st(hlds, pre, tid); __syncthreads();
    inner8(acc2, u2row + 256, h4base, kq8, bg);

    // ---- round A: z1 -> h1(t)  (skip at t==TT: L1(512) doesn't exist) ----
    __syncthreads();
    #pragma unroll
    for (int i = 0; i < 8; ++i) zred[kq * 544 + (bg * 8 + i) * 17 + zcl] = acc1[i];
    __syncthreads();
    if (tid < 128 && t < TT) {
      float z[4];
      #pragma unroll
      for (int g = 0; g < 4; ++g) {
        float s = 0.f;
        #pragma unroll
        for (int q = 0; q < 8; ++q) s += zred[q * 544 + fb * 17 + g * 4 + fc];
        z[g] = s;
      }
      int tok = tokens[(bh * 32 + fb) * TT + t];
      #pragma unroll
      for (int g = 0; g < 4; ++g) z[g] += tabw[tok * 16 + g * 4 + fc];
      float si = 1.f / (1.f + expf(-z[0]));
      float sf = 1.f / (1.f + expf(-z[1]));
      float gg = tanhf(z[2]);
      float so = 1.f / (1.f + expf(-z[3]));
      float cn = sf * c1 + si * gg;
      float hn = so * tanhf(cn);
      if (tok == 0) { cn = c1; hn = hp1; }
      c1 = cn; hp1 = hn;
      ic_store(h1w + (bh * 32 + fb) * HH + hc0 + fc, hn);
    }

    // ---- round B: z2 -> h2(t-1) ----
    __syncthreads();
    #pragma unroll
    for (int i = 0; i < 8; ++i) zred[kq * 544 + (bg * 8 + i) * 17 + zcl] = acc2[i];
    __syncthreads();
    if (tid < 128) {
      float z[4];
      #pragma unroll
      for (int g = 0; g < 4; ++g) {
        float s = 0.f;
        #pragma unroll
        for (int q = 0; q < 8; ++q) s += zred[q * 544 + fb * 17 + g * 4 + fc];
        z[g] = s + b2w[g * 4 + fc];
      }
      int tok = tokens[(bh * 32 + fb) * TT + (t - 1)];
      float si = 1.f / (1.f + expf(-z[0]));
      float sf = 1.f / (1.f + expf(-z[1]));
      float gg = tanhf(z[2]);
      float so = 1.f / (1.f + expf(-z[3]));
      float cn = sf * c2 + si * gg;
      float hn = so * tanhf(cn);
      if (tok == 0) { cn = c2; hn = hp2; }
      c2 = cn; hp2 = hn;
      ic_store(h2w + (bh * 32 + fb) * HH + hc0 + fc, hn);
    }

    bar_publish(myF, (unsigned)t + 2u);
  }

  // ---------------- final dense: out = h2(511) @ Wd + bd ----------------
  bar_wait(fHalf, (unsigned)TT + 2u);          // all h2(511) visible
  const float* h2f = h2base + BB * HH;         // gen 511 -> buf[1]
  if (ct < 4) {
    int idx = ct * 512 + tid;                  // 0..2047 per half
    int b = idx >> 6, f = idx & 63;
    const float* hf = h2f + (bh * 32 + b) * HH;
    float a = bd[f];
    #pragma unroll 4
    for (int k = 0; k < HH; k += 2) {
      float2 hv = ic_load2(hf + k);
      a += hv.x * Wd[(size_t)k * FF + f];
      a += hv.y * Wd[(size_t)(k + 1) * FF + f];
    }
    out[(bh * 32 + b) * FF + f] = a;
  }
}

extern "C" void kernel_launch(void* const* d_in, const int* in_sizes, int n_in,
                              void* d_out, int out_size, void* d_ws, size_t ws_size,
                              hipStream_t stream) {
  const int*   tokens = (const int*)  d_in[0];
  const float* emb    = (const float*)d_in[1];
  const float* W1     = (const float*)d_in[2];
  const float* U1     = (const float*)d_in[3];
  const float* b1     = (const float*)d_in[4];
  const float* W2     = (const float*)d_in[5];
  const float* U2     = (const float*)d_in[6];
  const float* b2     = (const float*)d_in[7];
  const float* Wd     = (const float*)d_in[8];
  const float* bd     = (const float*)d_in[9];
  float*    out   = (float*)d_out;
  unsigned* flags = (unsigned*)d_ws;
  float*    wsf   = (float*)((char*)d_ws + FLAG_WORDS * 4);

  // Host-side module attribute (graph-capture safe); needed for >64 KB LDS.
  hipFuncSetAttribute((const void*)lstm_fused5,
                      hipFuncAttributeMaxDynamicSharedMemorySize, LDS_BYTES);

  hipMemsetAsync(d_ws, 0, FLAG_WORDS * 4, stream);   // zero flag region

  void* args[] = { &tokens, &emb, &W1, &U1, &b1, &W2, &U2, &b2, &Wd, &bd,
                   &out, &wsf, &flags };
  hipLaunchCooperativeKernel((void*)lstm_fused5, dim3(NWG), dim3(NTHR),
                             args, LDS_BYTES, stream);
}